// Round 10
// baseline (112.697 us; speedup 1.0000x reference)
//
#include <hip/hip_runtime.h>
#include <hip/hip_bf16.h>
#include <math.h>

// Steerable CNP target prediction — separable RBF + bf16 MFMA, single kernel.
//
// out[t,c] = (sum_i Kx[t,i] * V[t,c,i]) / (Sx[t]*Sy[t]),
//   V[t,c,i] = sum_j Ky[t,j] * FMc[j,i]   <- GEMM: mfma_f32_16x16x32_bf16
// Kx,Ky,Sx,Sy in fp32 (exact denominators); Ky/FM rounded to bf16 for MFMA.
//
// Round 10 vs round 9 (16.1us): pack_pre launch eliminated. B-fragments are
// gathered per-wave directly from fm (8 imm-offset dword loads per frag,
// L2-hot), softplus applied inline on the c>=2 waves, bf16 cvt in-register.
// Identical values to the packed path -> absmax must stay 0.00390625.

#define NA      128
#define TT      16
#define THREADS 512

typedef __attribute__((ext_vector_type(8))) short short8;
typedef __attribute__((ext_vector_type(4))) float f32x4;

__device__ __forceinline__ short f2bf(float x) {
    __hip_bfloat16 h = __float2bfloat16(x);
    return *reinterpret_cast<short*>(&h);
}

__global__ __launch_bounds__(THREADS)
void cnp_mfma(const float* __restrict__ fm,    // [4][NA][NA]
              const float* __restrict__ grid,  // [NA*NA][2]
              const float* __restrict__ xt,    // [T][2]
              const float* __restrict__ lsp,   // [1]
              float* __restrict__ out,         // means [T][2] then sigmas [T][2]
              int n_target)
{
    __shared__ __attribute__((aligned(16))) float Kx[TT * NA];      // 8 KB
    __shared__ __attribute__((aligned(16))) float Ky32[TT * NA];    // 8 KB
    __shared__ __attribute__((aligned(16))) short kyA[4 * 64 * 8];  // 4 KB, A-frags
    __shared__ float psx[TT], psy[TT];
    __shared__ float red[4][2][TT];

    const int tid  = threadIdx.x;
    const int wid  = tid >> 6;
    const int c    = wid & 3;         // channel
    const int nh   = wid >> 2;        // n-half (i-tiles nh*4 .. nh*4+3)
    const int lane = tid & 63;
    const int t0   = blockIdx.x * TT;

    const float l      = lsp[0];
    const float inv2l2 = 0.5f / (l * l);

    // ---- phase 0: exps -> LDS (Kx fp32, Ky fp32 + bf16 A-frag) ----
    // grid[g] = (ax[g>>7], ax[g&127])  =>  ax[j] = grid[j*2+1]
#pragma unroll
    for (int s = 0; s < 4; ++s) {
        const int k = s * THREADS + tid;   // 0..2047
        const int t = k >> 7;
        const int j = k & 127;
        int tg = t0 + t; if (tg >= n_target) tg = n_target - 1;
        const float ax = grid[j * 2 + 1];
        const float dx = xt[tg * 2 + 0] - ax;
        const float dy = xt[tg * 2 + 1] - ax;
        const float kxv = __expf(-dx * dx * inv2l2);
        const float kyv = __expf(-dy * dy * inv2l2);
        Kx[t * NA + j]   = kxv;
        Ky32[t * NA + j] = kyv;
        // Ky -> A-fragment layout: m = t (0..15), k-pos = j
        const int ss = j >> 5, g = (j & 31) >> 3, e = j & 7;
        kyA[((ss * 64) + g * 16 + (t & 15)) * 8 + e] = f2bf(kyv);
    }
    __syncthreads();

    // ---- Sx/Sy: one shallow reduce. 32 groups (t x axis) x 16 lanes ----
    {
        const int grp  = tid >> 4;        // 0..31
        const int l16  = tid & 15;
        const int t    = grp >> 1;
        const int axis = grp & 1;
        const float* kb = axis ? Ky32 : Kx;
        const float4 q0 = *reinterpret_cast<const float4*>(&kb[t * NA + l16 * 8]);
        const float4 q1 = *reinterpret_cast<const float4*>(&kb[t * NA + l16 * 8 + 4]);
        float u = ((q0.x + q0.y) + (q0.z + q0.w)) + ((q1.x + q1.y) + (q1.z + q1.w));
        u += __shfl_xor(u, 1); u += __shfl_xor(u, 2);
        u += __shfl_xor(u, 4); u += __shfl_xor(u, 8);
        if (l16 == 0) { if (axis) psy[t] = u; else psx[t] = u; }
    }

    // ---- A-frags (shared by all waves) ----
    const short8* kap = reinterpret_cast<const short8*>(kyA);
    const short8 a0 = kap[0 * 64 + lane];
    const short8 a1 = kap[1 * 64 + lane];
    const short8 a2 = kap[2 * 64 + lane];
    const short8 a3 = kap[3 * 64 + lane];

    // ---- phase 1+2: 4 n-tiles; B-frags gathered straight from fm ----
    const int icol = lane & 15;
    const int krow = (lane >> 4) * 8;     // first k of this lane's frag rows
    const int tb   = (lane >> 4) * 4;
    const bool sp  = (c >= 2);
    const float* fsrc = fm + c * NA * NA;
    f32x4 p = {0.f, 0.f, 0.f, 0.f};

#define GFRAG(FR, S, PTR)                                                      \
    {                                                                          \
        const float* pk = (PTR) + ((S) * 32 + krow) * NA;                      \
        _Pragma("unroll")                                                      \
        for (int e = 0; e < 8; ++e) {                                          \
            float v = pk[e * NA];                                              \
            if (sp) v = (v > 15.0f) ? v : log1pf(__expf(v));                   \
            FR[e] = f2bf(v);                                                   \
        }                                                                      \
    }

#pragma unroll
    for (int nn = 0; nn < 4; ++nn) {
        const int i = (nh * 4 + nn) * 16 + icol;
        const float* pb = fsrc + i;
        short8 b0, b1, b2, b3;
        GFRAG(b0, 0, pb) GFRAG(b1, 1, pb) GFRAG(b2, 2, pb) GFRAG(b3, 3, pb)
        f32x4 acc = {0.f, 0.f, 0.f, 0.f};
        acc = __builtin_amdgcn_mfma_f32_16x16x32_bf16(a0, b0, acc, 0, 0, 0);
        acc = __builtin_amdgcn_mfma_f32_16x16x32_bf16(a1, b1, acc, 0, 0, 0);
        acc = __builtin_amdgcn_mfma_f32_16x16x32_bf16(a2, b2, acc, 0, 0, 0);
        acc = __builtin_amdgcn_mfma_f32_16x16x32_bf16(a3, b3, acc, 0, 0, 0);
        p.x = fmaf(Kx[(tb + 0) * NA + i], acc.x, p.x);
        p.y = fmaf(Kx[(tb + 1) * NA + i], acc.y, p.y);
        p.z = fmaf(Kx[(tb + 2) * NA + i], acc.z, p.z);
        p.w = fmaf(Kx[(tb + 3) * NA + i], acc.w, p.w);
    }
#undef GFRAG

    // reduce over the 16 i-lanes (strides 1,2,4,8)
#pragma unroll
    for (int st = 1; st <= 8; st <<= 1) {
        p.x += __shfl_xor(p.x, st);
        p.y += __shfl_xor(p.y, st);
        p.z += __shfl_xor(p.z, st);
        p.w += __shfl_xor(p.w, st);
    }
    if ((lane & 15) == 0) {
        red[c][nh][tb + 0] = p.x;
        red[c][nh][tb + 1] = p.y;
        red[c][nh][tb + 2] = p.z;
        red[c][nh][tb + 3] = p.w;
    }
    __syncthreads();

    // ---- phase 3: combine n-halves, normalize, write (64 outputs) ----
    if (tid < 4 * TT) {
        const int t  = tid & (TT - 1);
        const int cc = tid >> 4;            // requires TT == 16
        const int tg = t0 + t;
        if (tg < n_target) {
            const float numer = red[cc][0][t] + red[cc][1][t];
            const float val = numer / (psx[t] * psy[t]);
            if (cc < 2) out[tg * 2 + cc] = val;                        // means
            else        out[n_target * 2 + tg * 2 + (cc - 2)] = val;   // sigmas
        }
    }
}

extern "C" void kernel_launch(void* const* d_in, const int* in_sizes, int n_in,
                              void* d_out, int out_size, void* d_ws, size_t ws_size,
                              hipStream_t stream) {
    const float* fm   = (const float*)d_in[0];
    const float* grid = (const float*)d_in[1];
    const float* xt   = (const float*)d_in[2];
    const float* lsp  = (const float*)d_in[3];
    float* out = (float*)d_out;

    const int n_target = in_sizes[2] / 2;          // 8192
    const int blocks = (n_target + TT - 1) / TT;   // 512
    hipLaunchKernelGGL(cnp_mfma, dim3(blocks), dim3(THREADS), 0, stream,
                       fm, grid, xt, lsp, out, n_target);
}

// Round 11
// 15.140 us; speedup vs baseline: 7.4435x; 7.4435x over previous
//
#include <hip/hip_runtime.h>
#include <hip/hip_bf16.h>
#include <math.h>

// Steerable CNP target prediction — separable RBF + bf16 MFMA.
//
// out[t,c] = (sum_i Kx[t,i] * V[t,c,i]) / (Sx[t]*Sy[t]),
//   V[t,c,i] = sum_j Ky[t,j] * FMc[j,i]   <- GEMM: mfma_f32_16x16x32_bf16
// Kx,Ky,Sx,Sy in fp32 (exact denominators); Ky/FM rounded to bf16 for MFMA.
//
// Round 11 = round 9 (16.1us best) + B-fragment prefetch: the 16 dwordx4
// loads of the packed B operand (from ws, independent of phase 0) are
// issued at kernel entry so their L2 latency hides under the exp/LDS/
// barrier phase instead of sitting on the post-barrier critical path.
// Round-10 lesson: never gather B per-lane from fm (uncoalesced, 7x slower).

#define NA      128
#define TT      16
#define THREADS 512

typedef __attribute__((ext_vector_type(8))) short short8;
typedef __attribute__((ext_vector_type(4))) float f32x4;

__device__ __forceinline__ short f2bf(float x) {
    __hip_bfloat16 h = __float2bfloat16(x);
    return *reinterpret_cast<short*>(&h);
}

// ---------- pre-kernel: FM -> softplus'd bf16 fragment-linear layout ----------
// bfB[(((c*8+n)*4+s)*64+L)*8+e] = FMc[k][i], k=s*32+((L>>4)&3)*8+e, i=n*16+(L&15)
__global__ __launch_bounds__(256)
void pack_pre(const float* __restrict__ fm, short* __restrict__ bfB)
{
    const int idx = blockIdx.x * 256 + threadIdx.x;   // 16384 = 4c x 128k x 32 i4
    const int c  = idx >> 12;
    const int k  = (idx >> 5) & 127;
    const int i0 = (idx & 31) * 4;

    float4 v = *reinterpret_cast<const float4*>(fm + c * NA * NA + k * NA + i0);
    if (c >= 2) {
        v.x = (v.x > 15.0f) ? v.x : log1pf(__expf(v.x));
        v.y = (v.y > 15.0f) ? v.y : log1pf(__expf(v.y));
        v.z = (v.z > 15.0f) ? v.z : log1pf(__expf(v.z));
        v.w = (v.w > 15.0f) ? v.w : log1pf(__expf(v.w));
    }
    const int s = k >> 5;
    const int e = k & 7;
    const int Lk = ((k >> 3) & 3) * 16;
    const float vv[4] = {v.x, v.y, v.z, v.w};
#pragma unroll
    for (int d = 0; d < 4; ++d) {
        const int i = i0 + d;
        const int n = i >> 4;
        const int L = Lk + (i & 15);
        bfB[(((c * 8 + n) * 4 + s) * 64 + L) * 8 + e] = f2bf(vv[d]);
    }
}

// ---------- main kernel ----------
__global__ __launch_bounds__(THREADS)
void cnp_mfma(const short* __restrict__ bfB,   // [4][8][4][64][8] bf16
              const float* __restrict__ grid,  // [NA*NA][2]
              const float* __restrict__ xt,    // [T][2]
              const float* __restrict__ lsp,   // [1]
              float* __restrict__ out,         // means [T][2] then sigmas [T][2]
              int n_target)
{
    __shared__ __attribute__((aligned(16))) float Kx[TT * NA];      // 8 KB
    __shared__ __attribute__((aligned(16))) float Ky32[TT * NA];    // 8 KB
    __shared__ __attribute__((aligned(16))) short kyA[4 * 64 * 8];  // 4 KB, A-frags
    __shared__ float psx[TT], psy[TT];
    __shared__ float red[4][2][TT];

    const int tid  = threadIdx.x;
    const int wid  = tid >> 6;
    const int c    = wid & 3;         // channel
    const int nh   = wid >> 2;        // n-half (i-tiles nh*4 .. nh*4+3)
    const int lane = tid & 63;
    const int t0   = blockIdx.x * TT;

    // ---- B-frag prefetch (independent of phase 0 — hide under it) ----
    const short8* bbase = reinterpret_cast<const short8*>(bfB)
                        + c * 2048 + nh * 4 * 256 + lane;   // (c*8+n)*256 + s*64 + L
    const short8 b00 = bbase[0],         b01 = bbase[64],
                 b02 = bbase[128],       b03 = bbase[192];
    const short8 b10 = bbase[256],       b11 = bbase[256 + 64],
                 b12 = bbase[256 + 128], b13 = bbase[256 + 192];
    const short8 b20 = bbase[512],       b21 = bbase[512 + 64],
                 b22 = bbase[512 + 128], b23 = bbase[512 + 192];
    const short8 b30 = bbase[768],       b31 = bbase[768 + 64],
                 b32 = bbase[768 + 128], b33 = bbase[768 + 192];

    const float l      = lsp[0];
    const float inv2l2 = 0.5f / (l * l);

    // ---- phase 0: exps -> LDS (Kx fp32, Ky fp32 + bf16 A-frag) ----
    // grid[g] = (ax[g>>7], ax[g&127])  =>  ax[j] = grid[j*2+1]
#pragma unroll
    for (int s = 0; s < 4; ++s) {
        const int k = s * THREADS + tid;   // 0..2047
        const int t = k >> 7;
        const int j = k & 127;
        int tg = t0 + t; if (tg >= n_target) tg = n_target - 1;
        const float ax = grid[j * 2 + 1];
        const float dx = xt[tg * 2 + 0] - ax;
        const float dy = xt[tg * 2 + 1] - ax;
        const float kxv = __expf(-dx * dx * inv2l2);
        const float kyv = __expf(-dy * dy * inv2l2);
        Kx[t * NA + j]   = kxv;
        Ky32[t * NA + j] = kyv;
        // Ky -> A-fragment layout: m = t (0..15), k-pos = j
        const int ss = j >> 5, g = (j & 31) >> 3, e = j & 7;
        kyA[((ss * 64) + g * 16 + (t & 15)) * 8 + e] = f2bf(kyv);
    }
    __syncthreads();

    // ---- Sx/Sy: one shallow reduce. 32 groups (t x axis) x 16 lanes ----
    {
        const int grp  = tid >> 4;        // 0..31
        const int l16  = tid & 15;
        const int t    = grp >> 1;
        const int axis = grp & 1;
        const float* kb = axis ? Ky32 : Kx;
        const float4 q0 = *reinterpret_cast<const float4*>(&kb[t * NA + l16 * 8]);
        const float4 q1 = *reinterpret_cast<const float4*>(&kb[t * NA + l16 * 8 + 4]);
        float u = ((q0.x + q0.y) + (q0.z + q0.w)) + ((q1.x + q1.y) + (q1.z + q1.w));
        u += __shfl_xor(u, 1); u += __shfl_xor(u, 2);
        u += __shfl_xor(u, 4); u += __shfl_xor(u, 8);
        if (l16 == 0) { if (axis) psy[t] = u; else psx[t] = u; }
    }

    // ---- A-frags (shared by all waves) ----
    const short8* kap = reinterpret_cast<const short8*>(kyA);
    const short8 a0 = kap[0 * 64 + lane];
    const short8 a1 = kap[1 * 64 + lane];
    const short8 a2 = kap[2 * 64 + lane];
    const short8 a3 = kap[3 * 64 + lane];

    // ---- phase 1+2: 4 n-tiles, each 4 MFMAs + Kx dot ----
    const int icol = lane & 15;
    const int tb   = (lane >> 4) * 4;
    f32x4 p = {0.f, 0.f, 0.f, 0.f};

#define NTILE(NN, B0, B1, B2, B3)                                              \
    {                                                                          \
        f32x4 acc = {0.f, 0.f, 0.f, 0.f};                                      \
        acc = __builtin_amdgcn_mfma_f32_16x16x32_bf16(a0, B0, acc, 0, 0, 0);   \
        acc = __builtin_amdgcn_mfma_f32_16x16x32_bf16(a1, B1, acc, 0, 0, 0);   \
        acc = __builtin_amdgcn_mfma_f32_16x16x32_bf16(a2, B2, acc, 0, 0, 0);   \
        acc = __builtin_amdgcn_mfma_f32_16x16x32_bf16(a3, B3, acc, 0, 0, 0);   \
        const int i = (nh * 4 + (NN)) * 16 + icol;                             \
        p.x = fmaf(Kx[(tb + 0) * NA + i], acc.x, p.x);                         \
        p.y = fmaf(Kx[(tb + 1) * NA + i], acc.y, p.y);                         \
        p.z = fmaf(Kx[(tb + 2) * NA + i], acc.z, p.z);                         \
        p.w = fmaf(Kx[(tb + 3) * NA + i], acc.w, p.w);                         \
    }
    NTILE(0, b00, b01, b02, b03)
    NTILE(1, b10, b11, b12, b13)
    NTILE(2, b20, b21, b22, b23)
    NTILE(3, b30, b31, b32, b33)
#undef NTILE

    // reduce over the 16 i-lanes (strides 1,2,4,8)
#pragma unroll
    for (int st = 1; st <= 8; st <<= 1) {
        p.x += __shfl_xor(p.x, st);
        p.y += __shfl_xor(p.y, st);
        p.z += __shfl_xor(p.z, st);
        p.w += __shfl_xor(p.w, st);
    }
    if ((lane & 15) == 0) {
        red[c][nh][tb + 0] = p.x;
        red[c][nh][tb + 1] = p.y;
        red[c][nh][tb + 2] = p.z;
        red[c][nh][tb + 3] = p.w;
    }
    __syncthreads();

    // ---- phase 3: combine n-halves, normalize, write (64 outputs) ----
    if (tid < 4 * TT) {
        const int t  = tid & (TT - 1);
        const int cc = tid >> 4;            // requires TT == 16
        const int tg = t0 + t;
        if (tg < n_target) {
            const float numer = red[cc][0][t] + red[cc][1][t];
            const float val = numer / (psx[t] * psy[t]);
            if (cc < 2) out[tg * 2 + cc] = val;                        // means
            else        out[n_target * 2 + tg * 2 + (cc - 2)] = val;   // sigmas
        }
    }
}

extern "C" void kernel_launch(void* const* d_in, const int* in_sizes, int n_in,
                              void* d_out, int out_size, void* d_ws, size_t ws_size,
                              hipStream_t stream) {
    const float* fm   = (const float*)d_in[0];
    const float* grid = (const float*)d_in[1];
    const float* xt   = (const float*)d_in[2];
    const float* lsp  = (const float*)d_in[3];
    float* out = (float*)d_out;
    short* bfB = (short*)d_ws;                     // 4*8*4*64*8 bf16 = 128 KB

    const int n_target = in_sizes[2] / 2;          // 8192

    hipLaunchKernelGGL(pack_pre, dim3(64), dim3(256), 0, stream, fm, bfB);

    const int blocks = (n_target + TT - 1) / TT;   // 512
    hipLaunchKernelGGL(cnp_mfma, dim3(blocks), dim3(THREADS), 0, stream,
                       bfB, grid, xt, lsp, out, n_target);
}